// Round 2
// baseline (292.917 us; speedup 1.0000x reference)
//
#include <hip/hip_runtime.h>

#define B_ 4
#define N_ 325
#define I_ 64
#define H_ 128
#define NODES (B_ * N_)
#define NZMAX 64                    // max nz/row ~35 (5% of 325 + self-loop)
#define NBLK (NODES / 4)            // 325 blocks, 4 nodes each

typedef unsigned short u16;
typedef unsigned int u32;

// f32 weight scratch, written each launch (converts + transposes).
__device__ __align__(16) float g_WT   [192 * 512];   // [k][g]  gates weights
__device__ __align__(16) float g_gcw  [128 * 128];   // [k][o]
__device__ __align__(16) float g_WsT  [128 * 128];   // [k][o]
__device__ __align__(16) float g_WtT  [128 * 128];   // [k][o]
__device__ __align__(16) float g_combT[256 * 128];   // [k][o]
__device__ float g_bias[512];                        // b_ih + b_hh
__device__ float g_svec[896];  // [0]=gc_b [128]=Ws_b [256]=Wt_b [384]=v [512]=ln_g [640]=ln_b [768]=comb_b

// activation scratch (cross-block only)
__device__ __align__(16) float g_support[(size_t)NODES * H_];
__device__ __align__(16) float g_h_graph[(size_t)NODES * H_];
__device__ __align__(16) float g_t_buf  [(size_t)NODES * H_];
// legacy-path-only scratch
__device__ __align__(16) float g_s_buf  [(size_t)NODES * H_];
__device__ __align__(16) float g_hl     [(size_t)NODES * H_];
__device__ u16 g_nz [(size_t)NODES * NZMAX];
__device__ int g_nzc[NODES];

// custom grid barrier state (persistent across launches; count always
// returns to 0, gen monotonically increases and is compared relatively)
__device__ int g_bar_count;
__device__ int g_bar_gen;

__device__ __forceinline__ float bf2f(u16 u) { return __uint_as_float(((u32)u) << 16); }
__device__ __forceinline__ u16 f2bf(float f) {
    u32 u = __float_as_uint(f);
    u += 0x7fffu + ((u >> 16) & 1u);   // RNE
    return (u16)(u >> 16);
}
__device__ __forceinline__ float ldin(const void* p, size_t i, int f32) {
    return f32 ? ((const float*)p)[i] : bf2f(((const u16*)p)[i]);
}
__device__ __forceinline__ void stout(void* p, size_t i, float v, int f32) {
    if (f32) ((float*)p)[i] = v; else ((u16*)p)[i] = f2bf(v);
}
__device__ __forceinline__ float fast_rcp(float x) { return __builtin_amdgcn_rcpf(x); }
__device__ __forceinline__ float sigm(float x) { return fast_rcp(1.f + __expf(-x)); }
__device__ __forceinline__ float tanh_f(float x) {
    x = fminf(15.f, fmaxf(-15.f, x));
    float e = __expf(2.f * x);
    return (e - 1.f) * fast_rcp(e + 1.f);
}
// adj[0,0]==1.0 (self-loop): fp32 low16 = 0x0000, bf16 low16 = 0x3F80.
__device__ __forceinline__ int probe_f32(const void* adj) {
    return ((((const u32*)adj)[0] & 0xFFFFu) != 0x3F80u) ? 1 : 0;
}

// ---------------------------------------------------------------------------
// Lightweight sense-reversing grid barrier. One agent-scope RMW per block +
// tight acquire-load spin (s_sleep(2) ~128cy between polls). Leader-only
// agent fences cover the whole block's writes (all waves share one CU's
// caches) -- same physical pattern as ockl's grid sync, minus the overhead.
// Requires all NBLK blocks co-resident (guaranteed via cooperative launch).
// ---------------------------------------------------------------------------
__device__ __forceinline__ void gridbar() {
    __syncthreads();
    if (threadIdx.x == 0) {
        const int gen = __hip_atomic_load(&g_bar_gen, __ATOMIC_RELAXED,
                                          __HIP_MEMORY_SCOPE_AGENT);
        const int prev = __hip_atomic_fetch_add(&g_bar_count, 1, __ATOMIC_ACQ_REL,
                                                __HIP_MEMORY_SCOPE_AGENT);
        if (prev == NBLK - 1) {
            __hip_atomic_store(&g_bar_count, 0, __ATOMIC_RELAXED,
                               __HIP_MEMORY_SCOPE_AGENT);
            __hip_atomic_store(&g_bar_gen, gen + 1, __ATOMIC_RELEASE,
                               __HIP_MEMORY_SCOPE_AGENT);
        } else {
            while (__hip_atomic_load(&g_bar_gen, __ATOMIC_ACQUIRE,
                                     __HIP_MEMORY_SCOPE_AGENT) == gen)
                __builtin_amdgcn_s_sleep(2);
        }
    }
    __syncthreads();
}

#define PREP_TOT (98304 + 16384 * 3 + 32768 + 512 + 896)

__device__ __forceinline__ void prep_elem(int e, int f32,
    const void* W_ih, const void* W_hh, const void* b_ih, const void* b_hh,
    const void* gc_w, const void* gc_b, const void* Ws_w, const void* Ws_b,
    const void* Wt_w, const void* Wt_b, const void* vvec, const void* ln_g,
    const void* ln_b, const void* comb_w, const void* comb_b)
{
    int i = e;
    if (i < 98304) {                                   // WT[k][g]
        const int k = i >> 9, g = i & 511;
        g_WT[i] = (k < 64) ? ldin(W_ih, (size_t)g * 64 + k, f32)
                           : ldin(W_hh, (size_t)g * 128 + (k - 64), f32);
        return;
    }
    i -= 98304;
    if (i < 16384) { g_gcw[i] = ldin(gc_w, i, f32); return; }
    i -= 16384;
    if (i < 16384) {                                   // WsT[k][o]
        const int k = i >> 7, o = i & 127;
        g_WsT[i] = ldin(Ws_w, (size_t)o * 128 + k, f32);
        return;
    }
    i -= 16384;
    if (i < 16384) {
        const int k = i >> 7, o = i & 127;
        g_WtT[i] = ldin(Wt_w, (size_t)o * 128 + k, f32);
        return;
    }
    i -= 16384;
    if (i < 32768) {                                   // combT[k][o]
        const int k = i >> 7, o = i & 127;
        g_combT[i] = ldin(comb_w, (size_t)o * 256 + k, f32);
        return;
    }
    i -= 32768;
    if (i < 512) { g_bias[i] = ldin(b_ih, i, f32) + ldin(b_hh, i, f32); return; }
    i -= 512;
    {
        const int seg = i >> 7, k = i & 127;
        const void* src = (seg == 0) ? gc_b : (seg == 1) ? Ws_b : (seg == 2) ? Wt_b :
                          (seg == 3) ? vvec : (seg == 4) ? ln_g : (seg == 5) ? ln_b : comb_b;
        g_svec[i] = ldin(src, k, f32);
    }
}

// ===========================================================================
// Fused kernel: prep -> LSTM+support -> gather+proj -> attn+out.
// 3 custom grid barriers at the true cross-block dependency edges.
// ===========================================================================
__global__ __launch_bounds__(512, 4) void k_fused(
    const void* __restrict__ x, const void* __restrict__ adj,
    const void* __restrict__ h, const void* __restrict__ c,
    const void* __restrict__ W_ih, const void* __restrict__ W_hh,
    const void* __restrict__ b_ih, const void* __restrict__ b_hh,
    const void* __restrict__ gc_w, const void* __restrict__ gc_b,
    const void* __restrict__ Ws_w, const void* __restrict__ Ws_b,
    const void* __restrict__ Wt_w, const void* __restrict__ Wt_b,
    const void* __restrict__ vvec, const void* __restrict__ ln_g,
    const void* __restrict__ ln_b, const void* __restrict__ comb_w,
    const void* __restrict__ comb_b, void* __restrict__ out)
{
    const int f32 = probe_f32(adj);
    const int t = threadIdx.x;
    const int node0 = blockIdx.x * 4;
    const int lane = t & 63, w = t >> 6;

    __shared__ __align__(16) float4 xh4[192];    // [k] x {n0..n3}
    __shared__ __align__(16) float4 Gt4[512];    // [g] x {n0..n3}
    __shared__ __align__(16) float4 hl4[128];    // h_lstm, lives to combine
    __shared__ __align__(16) float4 hg4[128];    // h_graph
    __shared__ __align__(16) float4 att4[128];   // normalized attention
    __shared__ u16 nzi[4][NZMAX];
    __shared__ float nzv[4][NZMAX];
    __shared__ float nzs[4][NZMAX];
    __shared__ int cnt[4];
    __shared__ float s_i[4][H_];
    __shared__ float red[4][H_];
    __shared__ float part[4][4][H_];
    __shared__ float mu_[4], rstd_[4], smv[4];

    // ---- Phase 0: weight prep (grid-strided over all blocks) ----
    {
        const int tid = blockIdx.x * 512 + t;
        const int nth = gridDim.x * 512;
        for (int e = tid; e < PREP_TOT; e += nth)
            prep_elem(e, f32, W_ih, W_hh, b_ih, b_hh, gc_w, gc_b, Ws_w, Ws_b,
                      Wt_w, Wt_b, vvec, ln_g, ln_b, comb_w, comb_b);
    }
    gridbar();

    // ---- Phase 1: gates -> cell -> support ----
    for (int e = t; e < 768; e += 512) {
        const int n = e / 192, k = e % 192;
        const int node = node0 + n;
        ((float*)&xh4[k])[n] = (k < 64) ? ldin(x, (size_t)node * 64 + k, f32)
                                        : ldin(h, (size_t)node * 128 + (k - 64), f32);
    }
    __syncthreads();
    {
        const int g = t;
        float a0 = 0.f, a1 = 0.f, a2 = 0.f, a3 = 0.f;
        #pragma unroll 8
        for (int k = 0; k < 192; ++k) {
            const float wv = g_WT[(size_t)k * 512 + g];
            const float4 xv = xh4[k];
            a0 = fmaf(xv.x, wv, a0); a1 = fmaf(xv.y, wv, a1);
            a2 = fmaf(xv.z, wv, a2); a3 = fmaf(xv.w, wv, a3);
        }
        const float bias = g_bias[g];
        Gt4[g] = make_float4(a0 + bias, a1 + bias, a2 + bias, a3 + bias);
    }
    __syncthreads();
    {
        const int n = t >> 7, hh = t & 127;
        const int node = node0 + n;
        float ig = ((const float*)&Gt4[hh])[n];
        float fg = ((const float*)&Gt4[128 + hh])[n];
        float gv = ((const float*)&Gt4[256 + hh])[n];
        float og = ((const float*)&Gt4[384 + hh])[n];
        float cl = sigm(fg) * ldin(c, (size_t)node * 128 + hh, f32) + sigm(ig) * tanh_f(gv);
        float hv = sigm(og) * tanh_f(cl);
        stout(out, (size_t)(NODES * H_) + (size_t)node * 128 + hh, cl, f32);
        ((float*)&hl4[hh])[n] = hv;
    }
    __syncthreads();
    {
        const int o = t & 127, n = t >> 7;     // n wave-uniform
        float acc = 0.f;
        #pragma unroll 8
        for (int k = 0; k < 128; ++k)
            acc = fmaf(((const float*)&hl4[k])[n], g_gcw[(size_t)k * 128 + o], acc);
        g_support[(size_t)(node0 + n) * 128 + o] = acc;
    }
    gridbar();

    // ---- Phase 2: nz compaction + h_graph gather + s/t projections ----
    if (t < 4) cnt[t] = 0;
    __syncthreads();
    {
        const int n = t >> 7, jj = t & 127;    // 128 threads per adjacency row
        const size_t row = (size_t)(node0 + n) * N_;
        for (int j = jj; j < N_; j += 128) {
            float a = ldin(adj, row + j, f32);
            if (a != 0.f) {
                int p = atomicAdd(&cnt[n], 1);
                if (p < NZMAX) { nzi[n][p] = (u16)j; nzv[n][p] = a; }
            }
        }
    }
    __syncthreads();
    {
        const int n = t >> 7, o = t & 127;     // all 4 nodes in one pass
        const int node = node0 + n;
        const int bn = node / N_;
        const int cn = min(cnt[n], NZMAX);
        float acc = g_svec[o];                 // gc_b
        for (int p = 0; p < cn; ++p)
            acc = fmaf(nzv[n][p], g_support[((size_t)bn * N_ + nzi[n][p]) * 128 + o], acc);
        g_h_graph[(size_t)node * 128 + o] = acc;
        ((float*)&hg4[o])[n] = acc;
    }
    __syncthreads();
    {
        // 512 threads: which = s/t, half = K-half; partials reduced via LDS
        const int o = t & 127;
        const int which = (t >> 7) & 1;
        const int half  = t >> 8;
        const float* WT = which ? g_WtT : g_WsT;
        const int k0 = half * 64;
        float a0 = 0.f, a1 = 0.f, a2 = 0.f, a3 = 0.f;
        #pragma unroll 8
        for (int kk = 0; kk < 64; ++kk) {
            const int k = k0 + kk;
            const float wv = WT[(size_t)k * 128 + o];
            const float4 hv = hg4[k];
            a0 = fmaf(hv.x, wv, a0); a1 = fmaf(hv.y, wv, a1);
            a2 = fmaf(hv.z, wv, a2); a3 = fmaf(hv.w, wv, a3);
        }
        const int s = which * 2 + half;
        part[s][0][o] = a0; part[s][1][o] = a1;
        part[s][2][o] = a2; part[s][3][o] = a3;
    }
    __syncthreads();
    for (int e = t; e < 1024; e += 512) {
        const int which = e >> 9, n = (e >> 7) & 3, o = e & 127;
        const float vsum = part[which * 2][n][o] + part[which * 2 + 1][n][o]
                         + g_svec[128 + which * 128 + o];
        if (which) g_t_buf[(size_t)(node0 + n) * 128 + o] = vsum;
        else       s_i[n][o] = vsum;           // s stays in LDS (own node only)
    }
    gridbar();

    // ---- Phase 3: scores + softmax + context + LN + combine ----
    {
        const int n = w & 3;                   // 2 waves per node, alternate p
        const int bn = (node0 + n) / N_;
        const int cn = min(cnt[n], NZMAX);
        const float v0 = g_svec[384 + lane], v1 = g_svec[384 + 64 + lane];
        const float si0 = s_i[n][lane], si1 = s_i[n][lane + 64];
        for (int p = (w >> 2); p < cn; p += 2) {
            const float* tj = g_t_buf + ((size_t)bn * N_ + nzi[n][p]) * 128;
            float a = v0 * tanh_f(si0 + tj[lane]) + v1 * tanh_f(si1 + tj[lane + 64]);
            #pragma unroll
            for (int off = 32; off > 0; off >>= 1) a += __shfl_xor(a, off);
            if (lane == 0) nzs[n][p] = a;
        }
    }
    __syncthreads();
    if (t < 4) {
        const int cn = min(cnt[t], NZMAX);
        float m = -1e30f;
        for (int p = 0; p < cn; ++p) m = fmaxf(m, nzs[t][p]);
        float ssum = 0.f;
        for (int p = 0; p < cn; ++p) { float e = __expf(nzs[t][p] - m); nzs[t][p] = e; ssum += e; }
        smv[t] = fast_rcp(ssum);
    }
    __syncthreads();
    {
        const int n = t >> 7, o = t & 127;     // all 4 nodes in one pass
        const int bn = (node0 + n) / N_;
        const int cn = min(cnt[n], NZMAX);
        float acc = 0.f;
        for (int p = 0; p < cn; ++p)
            acc = fmaf(nzs[n][p], g_h_graph[((size_t)bn * N_ + nzi[n][p]) * 128 + o], acc);
        red[n][o] = acc * smv[n];
    }
    __syncthreads();
    if (w < 4) {
        float x0 = red[w][lane], x1 = red[w][lane + 64];
        float sm = x0 + x1, sq = x0 * x0 + x1 * x1;
        #pragma unroll
        for (int off = 32; off > 0; off >>= 1) {
            sm += __shfl_xor(sm, off);
            sq += __shfl_xor(sq, off);
        }
        if (lane == 0) {
            float mu = sm * (1.f / H_);
            float var = fmaxf(sq * (1.f / H_) - mu * mu, 0.f);
            mu_[w] = mu;
            rstd_[w] = __builtin_amdgcn_rsqf(var + 1e-5f);
        }
    }
    __syncthreads();
    {
        const int n = t >> 7, k = t & 127;
        float xn = (red[n][k] - mu_[n]) * rstd_[n];
        ((float*)&att4[k])[n] = g_svec[512 + k] * xn + g_svec[640 + k];
    }
    __syncthreads();
    {
        // combine: quarter q covers K-slice [q*64, q*64+64); k<128 -> hl4
        const int o = t & 127, q = t >> 7;     // q wave-uniform
        const float4* src = (q < 2) ? hl4 : att4;
        const int kb = (q < 2) ? q * 64 : (q - 2) * 64;
        const int k0 = q * 64;
        float a0 = 0.f, a1 = 0.f, a2 = 0.f, a3 = 0.f;
        #pragma unroll 8
        for (int kk = 0; kk < 64; ++kk) {
            const float wv = g_combT[(size_t)(k0 + kk) * 128 + o];
            const float4 cv = src[kb + kk];
            a0 = fmaf(cv.x, wv, a0); a1 = fmaf(cv.y, wv, a1);
            a2 = fmaf(cv.z, wv, a2); a3 = fmaf(cv.w, wv, a3);
        }
        part[q][0][o] = a0; part[q][1][o] = a1;
        part[q][2][o] = a2; part[q][3][o] = a3;
    }
    __syncthreads();
    {
        const int n = t >> 7, k = t & 127;
        stout(out, (size_t)(node0 + n) * 128 + k,
              part[0][n][k] + part[1][n][k] + part[2][n][k] + part[3][n][k]
              + g_svec[768 + k], f32);
    }
}

// ===========================================================================
// Legacy 4-kernel fallback (proven path) in case cooperative launch is
// rejected by the runtime/capture.
// ===========================================================================
__global__ __launch_bounds__(256) void k0_prep(
    const void* __restrict__ W_ih, const void* __restrict__ W_hh,
    const void* __restrict__ b_ih, const void* __restrict__ b_hh,
    const void* __restrict__ gc_w, const void* __restrict__ gc_b,
    const void* __restrict__ Ws_w, const void* __restrict__ Ws_b,
    const void* __restrict__ Wt_w, const void* __restrict__ Wt_b,
    const void* __restrict__ vvec, const void* __restrict__ ln_g,
    const void* __restrict__ ln_b, const void* __restrict__ comb_w,
    const void* __restrict__ comb_b, const void* __restrict__ adj)
{
    const int f32 = probe_f32(adj);
    const int tid = blockIdx.x * 256 + threadIdx.x;
    const int nth = gridDim.x * 256;
    for (int e = tid; e < PREP_TOT; e += nth)
        prep_elem(e, f32, W_ih, W_hh, b_ih, b_hh, gc_w, gc_b, Ws_w, Ws_b,
                  Wt_w, Wt_b, vvec, ln_g, ln_b, comb_w, comb_b);
}

__global__ __launch_bounds__(512) void k1_lstm(
    const void* __restrict__ x, const void* __restrict__ h, const void* __restrict__ c,
    const void* __restrict__ adj, void* __restrict__ out)
{
    const int f32 = probe_f32(adj);
    __shared__ __align__(16) float4 xh4[192];
    __shared__ __align__(16) float4 Gt4[512];
    __shared__ __align__(16) float4 hl4[128];
    const int node0 = blockIdx.x * 4;
    const int t = threadIdx.x;

    for (int e = t; e < 768; e += 512) {
        const int n = e / 192, k = e % 192;
        const int node = node0 + n;
        ((float*)&xh4[k])[n] = (k < 64) ? ldin(x, (size_t)node * 64 + k, f32)
                                        : ldin(h, (size_t)node * 128 + (k - 64), f32);
    }
    __syncthreads();
    {
        const int g = t;
        float a0 = 0.f, a1 = 0.f, a2 = 0.f, a3 = 0.f;
        #pragma unroll 8
        for (int k = 0; k < 192; ++k) {
            const float wv = g_WT[(size_t)k * 512 + g];
            const float4 xv = xh4[k];
            a0 = fmaf(xv.x, wv, a0); a1 = fmaf(xv.y, wv, a1);
            a2 = fmaf(xv.z, wv, a2); a3 = fmaf(xv.w, wv, a3);
        }
        const float bias = g_bias[g];
        Gt4[g] = make_float4(a0 + bias, a1 + bias, a2 + bias, a3 + bias);
    }
    __syncthreads();
    {
        const int n = t >> 7, hh = t & 127;
        const int node = node0 + n;
        float ig = ((const float*)&Gt4[hh])[n];
        float fg = ((const float*)&Gt4[128 + hh])[n];
        float gv = ((const float*)&Gt4[256 + hh])[n];
        float og = ((const float*)&Gt4[384 + hh])[n];
        float cl = sigm(fg) * ldin(c, (size_t)node * 128 + hh, f32) + sigm(ig) * tanh_f(gv);
        float hv = sigm(og) * tanh_f(cl);
        stout(out, (size_t)(NODES * H_) + (size_t)node * 128 + hh, cl, f32);
        g_hl[(size_t)node * 128 + hh] = hv;
        ((float*)&hl4[hh])[n] = hv;
    }
    __syncthreads();
    {
        const int o = t & 127, n = t >> 7;
        float acc = 0.f;
        #pragma unroll 8
        for (int k = 0; k < 128; ++k)
            acc = fmaf(((const float*)&hl4[k])[n], g_gcw[(size_t)k * 128 + o], acc);
        g_support[(size_t)(node0 + n) * 128 + o] = acc;
    }
}

__global__ __launch_bounds__(256) void k2_graph(const void* __restrict__ adj)
{
    const int f32 = probe_f32(adj);
    __shared__ __align__(16) float4 hg4[128];
    __shared__ u16 nzi[4][NZMAX];
    __shared__ float nzv[4][NZMAX];
    __shared__ int cnt[4];
    const int node0 = blockIdx.x * 4;
    const int t = threadIdx.x;
    const int lane = t & 63, w = t >> 6;

    if (t < 4) cnt[t] = 0;
    __syncthreads();
    for (int j = lane; j < N_; j += 64) {
        float a = ldin(adj, (size_t)(node0 + w) * N_ + j, f32);
        if (a != 0.f) {
            int p = atomicAdd(&cnt[w], 1);
            if (p < NZMAX) { nzi[w][p] = (u16)j; nzv[w][p] = a; }
        }
    }
    __syncthreads();
    if (t < 4) g_nzc[node0 + t] = min(cnt[t], NZMAX);
    #pragma unroll
    for (int n = 0; n < 4; ++n) {
        const int cnn = min(cnt[n], NZMAX);
        for (int p = t; p < cnn; p += 256) g_nz[(size_t)(node0 + n) * NZMAX + p] = nzi[n][p];
    }

    const int o = t & 127;
    const float gb = g_svec[o];
    #pragma unroll
    for (int ps = 0; ps < 2; ++ps) {
        const int n = (t >> 7) + 2 * ps;
        const int node = node0 + n;
        const int bn = node / N_;
        const int cnn = min(cnt[n], NZMAX);
        float acc = gb;
        for (int p = 0; p < cnn; ++p)
            acc = fmaf(nzv[n][p], g_support[((size_t)bn * N_ + nzi[n][p]) * 128 + o], acc);
        g_h_graph[(size_t)node * 128 + o] = acc;
        ((float*)&hg4[o])[n] = acc;
    }
    __syncthreads();
    {
        const int which = t >> 7;
        const float* WT = which ? g_WtT : g_WsT;
        const float bias = g_svec[128 + which * 128 + o];
        float a0 = 0.f, a1 = 0.f, a2 = 0.f, a3 = 0.f;
        #pragma unroll 8
        for (int k = 0; k < 128; ++k) {
            const float wv = WT[(size_t)k * 128 + o];
            const float4 hv = hg4[k];
            a0 = fmaf(hv.x, wv, a0); a1 = fmaf(hv.y, wv, a1);
            a2 = fmaf(hv.z, wv, a2); a3 = fmaf(hv.w, wv, a3);
        }
        float* dst = which ? g_t_buf : g_s_buf;
        dst[(size_t)(node0 + 0) * 128 + o] = a0 + bias;
        dst[(size_t)(node0 + 1) * 128 + o] = a1 + bias;
        dst[(size_t)(node0 + 2) * 128 + o] = a2 + bias;
        dst[(size_t)(node0 + 3) * 128 + o] = a3 + bias;
    }
}

__global__ __launch_bounds__(256) void k3_attn(
    const void* __restrict__ adj, void* __restrict__ out)
{
    const int f32 = probe_f32(adj);
    __shared__ __align__(16) float4 comb4[256];
    __shared__ float s_i[4][H_];
    __shared__ float red[4][H_];
    __shared__ float nzs[4][NZMAX];
    __shared__ u16 nzi[4][NZMAX];
    __shared__ float part[2][4][H_];
    __shared__ float mu_[4], rstd_[4], smv[4];
    __shared__ int cnt[4];
    const int node0 = blockIdx.x * 4;
    const int t = threadIdx.x;
    const int lane = t & 63, w = t >> 6;

    if (t < 4) cnt[t] = g_nzc[node0 + t];
    for (int e = t; e < 512; e += 256) {
        const int n = e >> 7, k = e & 127;
        const int node = node0 + n;
        s_i[n][k] = g_s_buf[(size_t)node * 128 + k];
        ((float*)&comb4[k])[n] = g_hl[(size_t)node * 128 + k];
    }
    __syncthreads();
    #pragma unroll
    for (int n = 0; n < 4; ++n)
        for (int p = t; p < cnt[n]; p += 256) nzi[n][p] = g_nz[(size_t)(node0 + n) * NZMAX + p];
    __syncthreads();

    {
        const int bn = (node0 + w) / N_;
        const int cn = cnt[w];
        const float v0 = g_svec[384 + lane], v1 = g_svec[384 + 64 + lane];
        const float si0 = s_i[w][lane], si1 = s_i[w][lane + 64];
        for (int p = 0; p < cn; ++p) {
            const float* tj = g_t_buf + ((size_t)bn * N_ + nzi[w][p]) * 128;
            float a = v0 * tanh_f(si0 + tj[lane]) + v1 * tanh_f(si1 + tj[lane + 64]);
            #pragma unroll
            for (int off = 32; off > 0; off >>= 1) a += __shfl_xor(a, off);
            if (lane == 0) nzs[w][p] = a;
        }
    }
    __syncthreads();
    if (t < 4) {
        const int cn = cnt[t];
        float m = -1e30f;
        for (int p = 0; p < cn; ++p) m = fmaxf(m, nzs[t][p]);
        float ssum = 0.f;
        for (int p = 0; p < cn; ++p) { float e = __expf(nzs[t][p] - m); nzs[t][p] = e; ssum += e; }
        smv[t] = fast_rcp(ssum);
    }
    __syncthreads();
    const int o = t & 127;
    #pragma unroll
    for (int ps = 0; ps < 2; ++ps) {
        const int n = (t >> 7) + 2 * ps;
        const int bn = (node0 + n) / N_;
        const int cn = cnt[n];
        float acc = 0.f;
        for (int p = 0; p < cn; ++p)
            acc = fmaf(nzs[n][p], g_h_graph[((size_t)bn * N_ + nzi[n][p]) * 128 + o], acc);
        red[n][o] = acc * smv[n];
    }
    __syncthreads();
    {
        float x0 = red[w][lane], x1 = red[w][lane + 64];
        float sm = x0 + x1, sq = x0 * x0 + x1 * x1;
        #pragma unroll
        for (int off = 32; off > 0; off >>= 1) {
            sm += __shfl_xor(sm, off);
            sq += __shfl_xor(sq, off);
        }
        if (lane == 0) {
            float mu = sm * (1.f / H_);
            float var = fmaxf(sq * (1.f / H_) - mu * mu, 0.f);
            mu_[w] = mu;
            rstd_[w] = __builtin_amdgcn_rsqf(var + 1e-5f);
        }
    }
    __syncthreads();
    for (int e = t; e < 512; e += 256) {
        const int n = e >> 7, k = e & 127;
        float xn = (red[n][k] - mu_[n]) * rstd_[n];
        ((float*)&comb4[128 + k])[n] = g_svec[512 + k] * xn + g_svec[640 + k];
    }
    __syncthreads();
    {
        const int half = t >> 7;
        float a0 = 0.f, a1 = 0.f, a2 = 0.f, a3 = 0.f;
        const int k0 = half * 128;
        #pragma unroll 8
        for (int kk = 0; kk < 128; ++kk) {
            const int k = k0 + kk;
            const float wv = g_combT[(size_t)k * 128 + o];
            const float4 cv = comb4[k];
            a0 = fmaf(cv.x, wv, a0); a1 = fmaf(cv.y, wv, a1);
            a2 = fmaf(cv.z, wv, a2); a3 = fmaf(cv.w, wv, a3);
        }
        part[half][0][o] = a0; part[half][1][o] = a1;
        part[half][2][o] = a2; part[half][3][o] = a3;
    }
    __syncthreads();
    for (int e = t; e < 512; e += 256) {
        const int n = e >> 7, k = e & 127;
        stout(out, (size_t)(node0 + n) * 128 + k,
              part[0][n][k] + part[1][n][k] + g_svec[768 + k], f32);
    }
}

// ---------------------------------------------------------------------------
extern "C" void kernel_launch(void* const* d_in, const int* in_sizes, int n_in,
                              void* d_out, int out_size, void* d_ws, size_t ws_size,
                              hipStream_t stream)
{
    (void)in_sizes; (void)n_in; (void)out_size; (void)d_ws; (void)ws_size;
    const void* x      = d_in[0];
    const void* adj    = d_in[1];
    const void* h      = d_in[2];
    const void* c      = d_in[3];
    const void* W_ih   = d_in[4];
    const void* W_hh   = d_in[5];
    const void* b_ih   = d_in[6];
    const void* b_hh   = d_in[7];
    const void* gc_w   = d_in[8];
    const void* gc_b   = d_in[9];
    const void* Ws_w   = d_in[10];
    const void* Ws_b   = d_in[11];
    const void* Wt_w   = d_in[12];
    const void* Wt_b   = d_in[13];
    const void* vvec   = d_in[14];
    const void* ln_g   = d_in[15];
    const void* ln_b   = d_in[16];
    const void* comb_w = d_in[17];
    const void* comb_b = d_in[18];

    void* args[] = {
        (void*)&x, (void*)&adj, (void*)&h, (void*)&c,
        (void*)&W_ih, (void*)&W_hh, (void*)&b_ih, (void*)&b_hh,
        (void*)&gc_w, (void*)&gc_b, (void*)&Ws_w, (void*)&Ws_b,
        (void*)&Wt_w, (void*)&Wt_b, (void*)&vvec, (void*)&ln_g,
        (void*)&ln_b, (void*)&comb_w, (void*)&comb_b, (void*)&d_out
    };
    hipError_t err = hipLaunchCooperativeKernel(
        reinterpret_cast<void*>(k_fused), dim3(NBLK), dim3(512),
        args, 0, stream);
    if (err != hipSuccess) {
        // Fallback: proven 4-kernel path.
        k0_prep <<<256, 256, 0, stream>>>(W_ih, W_hh, b_ih, b_hh, gc_w, gc_b,
                                          Ws_w, Ws_b, Wt_w, Wt_b, vvec, ln_g, ln_b,
                                          comb_w, comb_b, adj);
        k1_lstm <<<NBLK, 512, 0, stream>>>(x, h, c, adj, d_out);
        k2_graph<<<NBLK, 256, 0, stream>>>(adj);
        k3_attn <<<NBLK, 256, 0, stream>>>(adj, d_out);
    }
}

// Round 3
// 162.805 us; speedup vs baseline: 1.7992x; 1.7992x over previous
//
#include <hip/hip_runtime.h>

#define B_ 4
#define N_ 325
#define I_ 64
#define H_ 128
#define NODES (B_ * N_)
#define NZMAX 64                    // max nz/row ~35 (5% of 325 + self-loop)
#define NBLK (NODES / 4)            // 325 blocks, 4 nodes each

typedef unsigned short u16;
typedef unsigned int u32;

// activation scratch (cross-block communication only)
__device__ __align__(16) float g_support[(size_t)NODES * H_];
__device__ __align__(16) float g_h_graph[(size_t)NODES * H_];
__device__ __align__(16) float g_t_buf  [(size_t)NODES * H_];
__device__ __align__(16) float g_s_buf  [(size_t)NODES * H_];
__device__ __align__(16) float g_hl     [(size_t)NODES * H_];
__device__ u16   g_nz [(size_t)NODES * NZMAX];
__device__ float g_nzw[(size_t)NODES * NZMAX];
__device__ int   g_nzc[NODES];

__device__ __forceinline__ float bf2f(u16 u) { return __uint_as_float(((u32)u) << 16); }
__device__ __forceinline__ u16 f2bf(float f) {
    u32 u = __float_as_uint(f);
    u += 0x7fffu + ((u >> 16) & 1u);   // RNE
    return (u16)(u >> 16);
}
template<int F32>
__device__ __forceinline__ float ldw(const void* p, size_t i) {
    return F32 ? ((const float*)p)[i] : bf2f(((const u16*)p)[i]);
}
template<int F32>
__device__ __forceinline__ float4 ldw4(const void* p, size_t i4) {
    if (F32) return ((const float4*)p)[i4];
    const ushort4 u = ((const ushort4*)p)[i4];
    return make_float4(bf2f(u.x), bf2f(u.y), bf2f(u.z), bf2f(u.w));
}
template<int F32>
__device__ __forceinline__ void stw(void* p, size_t i, float v) {
    if (F32) ((float*)p)[i] = v; else ((u16*)p)[i] = f2bf(v);
}
__device__ __forceinline__ float fast_rcp(float x) { return __builtin_amdgcn_rcpf(x); }
__device__ __forceinline__ float sigm(float x) { return fast_rcp(1.f + __expf(-x)); }
__device__ __forceinline__ float tanh_f(float x) {
    x = fminf(15.f, fmaxf(-15.f, x));
    float e = __expf(2.f * x);
    return (e - 1.f) * fast_rcp(e + 1.f);
}
// adj[0,0]==1.0 (self-loop): fp32 low16 = 0x0000, bf16 low16 = 0x3F80.
__device__ __forceinline__ int probe_f32(const void* adj) {
    return ((((const u32*)adj)[0] & 0xFFFFu) != 0x3F80u) ? 1 : 0;
}

// ===========================================================================
// D1: gates (raw W rows, float4) -> cell -> adjacency compaction -> support.
// 512 threads, 4 nodes/block.
// ===========================================================================
struct LdsA {
    float4 xh4[192];    // [k] x {n0..n3}
    float4 Gt4[512];    // [g] x {n0..n3}
    float4 hl4[128];    // [k] x {n0..n3}
    u16 nzi[4][NZMAX];
    float nzv[4][NZMAX];
    int cnt[4];
};

template<int F32>
__device__ __forceinline__ void d1_body(LdsA& S,
    const void* __restrict__ x, const void* __restrict__ adjp,
    const void* __restrict__ h, const void* __restrict__ c,
    const void* __restrict__ W_ih, const void* __restrict__ W_hh,
    const void* __restrict__ b_ih, const void* __restrict__ b_hh,
    const void* __restrict__ gc_w, void* __restrict__ out)
{
    const int t = threadIdx.x;
    const int node0 = blockIdx.x * 4;

    if (t < 4) S.cnt[t] = 0;
    for (int e = t; e < 768; e += 512) {
        const int n = e / 192, k = e % 192;
        const int node = node0 + n;
        ((float*)&S.xh4[k])[n] = (k < 64) ? ldw<F32>(x, (size_t)node * 64 + k)
                                          : ldw<F32>(h, (size_t)node * 128 + (k - 64));
    }
    __syncthreads();

    // gates: thread t owns gate row g; per-thread contiguous row reads
    {
        const int g = t;
        float a0 = 0.f, a1 = 0.f, a2 = 0.f, a3 = 0.f;
        #pragma unroll 4
        for (int k4 = 0; k4 < 16; ++k4) {          // W_ih row g: 64 elems
            const float4 wv = ldw4<F32>(W_ih, (size_t)g * 16 + k4);
            const float* wp = (const float*)&wv;
            #pragma unroll
            for (int j = 0; j < 4; ++j) {
                const float4 xv = S.xh4[k4 * 4 + j];
                a0 = fmaf(xv.x, wp[j], a0); a1 = fmaf(xv.y, wp[j], a1);
                a2 = fmaf(xv.z, wp[j], a2); a3 = fmaf(xv.w, wp[j], a3);
            }
        }
        #pragma unroll 4
        for (int k4 = 0; k4 < 32; ++k4) {          // W_hh row g: 128 elems
            const float4 wv = ldw4<F32>(W_hh, (size_t)g * 32 + k4);
            const float* wp = (const float*)&wv;
            #pragma unroll
            for (int j = 0; j < 4; ++j) {
                const float4 xv = S.xh4[64 + k4 * 4 + j];
                a0 = fmaf(xv.x, wp[j], a0); a1 = fmaf(xv.y, wp[j], a1);
                a2 = fmaf(xv.z, wp[j], a2); a3 = fmaf(xv.w, wp[j], a3);
            }
        }
        const float bias = ldw<F32>(b_ih, t) + ldw<F32>(b_hh, t);
        S.Gt4[g] = make_float4(a0 + bias, a1 + bias, a2 + bias, a3 + bias);
    }
    __syncthreads();

    // cell nonlinearity: t = (n, hh)
    {
        const int n = t >> 7, hh = t & 127;
        const int node = node0 + n;
        float ig = ((const float*)&S.Gt4[hh])[n];
        float fg = ((const float*)&S.Gt4[128 + hh])[n];
        float gv = ((const float*)&S.Gt4[256 + hh])[n];
        float og = ((const float*)&S.Gt4[384 + hh])[n];
        float cl = sigm(fg) * ldw<F32>(c, (size_t)node * 128 + hh) + sigm(ig) * tanh_f(gv);
        float hv = sigm(og) * tanh_f(cl);
        stw<F32>(out, (size_t)(NODES * H_) + (size_t)node * 128 + hh, cl);
        g_hl[(size_t)node * 128 + hh] = hv;
        ((float*)&S.hl4[hh])[n] = hv;
    }
    // adjacency compaction (independent of cell; cnt zeroed pre-first-sync)
    {
        const int n = t >> 7, jj = t & 127;
        const size_t row = (size_t)(node0 + n) * N_;
        for (int j = jj; j < N_; j += 128) {
            float a = ldw<F32>(adjp, row + j);
            if (a != 0.f) {
                int p = atomicAdd(&S.cnt[n], 1);
                if (p < NZMAX) { S.nzi[n][p] = (u16)j; S.nzv[n][p] = a; }
            }
        }
    }
    __syncthreads();

    // nz lists -> global
    if (t < 4) g_nzc[node0 + t] = min(S.cnt[t], NZMAX);
    #pragma unroll
    for (int n = 0; n < 4; ++n) {
        const int cnn = min(S.cnt[n], NZMAX);
        for (int p = t; p < cnn; p += 512) {
            g_nz [(size_t)(node0 + n) * NZMAX + p] = S.nzi[n][p];
            g_nzw[(size_t)(node0 + n) * NZMAX + p] = S.nzv[n][p];
        }
    }
    // support: raw gc_w[k][o] is already coalesced over o-threads
    {
        const int o = t & 127, n = t >> 7;         // n wave-uniform
        float acc = 0.f;
        #pragma unroll 8
        for (int k = 0; k < 128; ++k)
            acc = fmaf(((const float*)&S.hl4[k])[n], ldw<F32>(gc_w, (size_t)k * 128 + o), acc);
        g_support[(size_t)(node0 + n) * 128 + o] = acc;
    }
}

__global__ __launch_bounds__(512) void kd1(
    const void* __restrict__ x, const void* __restrict__ adj,
    const void* __restrict__ h, const void* __restrict__ c,
    const void* __restrict__ W_ih, const void* __restrict__ W_hh,
    const void* __restrict__ b_ih, const void* __restrict__ b_hh,
    const void* __restrict__ gc_w, void* __restrict__ out)
{
    __shared__ LdsA S;
    if (probe_f32(adj)) d1_body<1>(S, x, adj, h, c, W_ih, W_hh, b_ih, b_hh, gc_w, out);
    else                d1_body<0>(S, x, adj, h, c, W_ih, W_hh, b_ih, b_hh, gc_w, out);
}

// ===========================================================================
// D2: h_graph gather + s/t projections (raw Ws/Wt rows). 256 thr, 4 nodes.
// ===========================================================================
struct LdsB {
    float4 hg4[128];
    u16 nzi[4][NZMAX];
    float nzv[4][NZMAX];
    int cnt[4];
};

template<int F32>
__device__ __forceinline__ void d2_body(LdsB& S,
    const void* __restrict__ gc_b, const void* __restrict__ Ws_w,
    const void* __restrict__ Ws_b, const void* __restrict__ Wt_w,
    const void* __restrict__ Wt_b)
{
    const int t = threadIdx.x;
    const int node0 = blockIdx.x * 4;

    if (t < 4) S.cnt[t] = g_nzc[node0 + t];
    __syncthreads();
    #pragma unroll
    for (int n = 0; n < 4; ++n) {
        const int cnn = S.cnt[n];
        for (int p = t; p < cnn; p += 256) {
            S.nzi[n][p] = g_nz [(size_t)(node0 + n) * NZMAX + p];
            S.nzv[n][p] = g_nzw[(size_t)(node0 + n) * NZMAX + p];
        }
    }
    __syncthreads();

    const int o = t & 127;
    #pragma unroll
    for (int ps = 0; ps < 2; ++ps) {
        const int n = (t >> 7) + 2 * ps;
        const int node = node0 + n;
        const int bn = node / N_;
        const int cnn = S.cnt[n];
        float acc = ldw<F32>(gc_b, o);
        for (int p = 0; p < cnn; ++p)
            acc = fmaf(S.nzv[n][p], g_support[((size_t)bn * N_ + S.nzi[n][p]) * 128 + o], acc);
        g_h_graph[(size_t)node * 128 + o] = acc;
        ((float*)&S.hg4[o])[n] = acc;
    }
    __syncthreads();

    // s (t<128) / t (t>=128): thread o reads raw weight row o contiguously
    {
        const int which = t >> 7;
        const void* W = which ? Wt_w : Ws_w;
        const float bias = ldw<F32>(which ? Wt_b : Ws_b, o);
        float a0 = 0.f, a1 = 0.f, a2 = 0.f, a3 = 0.f;
        #pragma unroll 4
        for (int k4 = 0; k4 < 32; ++k4) {          // row o: 128 elems
            const float4 wv = ldw4<F32>(W, (size_t)o * 32 + k4);
            const float* wp = (const float*)&wv;
            #pragma unroll
            for (int j = 0; j < 4; ++j) {
                const float4 hv = S.hg4[k4 * 4 + j];
                a0 = fmaf(hv.x, wp[j], a0); a1 = fmaf(hv.y, wp[j], a1);
                a2 = fmaf(hv.z, wp[j], a2); a3 = fmaf(hv.w, wp[j], a3);
            }
        }
        float* dst = which ? g_t_buf : g_s_buf;
        dst[(size_t)(node0 + 0) * 128 + o] = a0 + bias;
        dst[(size_t)(node0 + 1) * 128 + o] = a1 + bias;
        dst[(size_t)(node0 + 2) * 128 + o] = a2 + bias;
        dst[(size_t)(node0 + 3) * 128 + o] = a3 + bias;
    }
}

__global__ __launch_bounds__(256) void kd2(
    const void* __restrict__ adj, const void* __restrict__ gc_b,
    const void* __restrict__ Ws_w, const void* __restrict__ Ws_b,
    const void* __restrict__ Wt_w, const void* __restrict__ Wt_b)
{
    __shared__ LdsB S;
    if (probe_f32(adj)) d2_body<1>(S, gc_b, Ws_w, Ws_b, Wt_w, Wt_b);
    else                d2_body<0>(S, gc_b, Ws_w, Ws_b, Wt_w, Wt_b);
}

// ===========================================================================
// D3: scores + softmax + context + LN + combine (raw comb rows). 256 thr.
// ===========================================================================
struct LdsC {
    float4 comb4[256];      // [k] x {n0..n3}: [h_lstm | h_att]
    float s_i[4][H_];
    float red[4][H_];
    float nzs[4][NZMAX];
    u16 nzi[4][NZMAX];
    float part[2][4][H_];
    float mu_[4], rstd_[4], smv[4];
    int cnt[4];
};

template<int F32>
__device__ __forceinline__ void d3_body(LdsC& S,
    const void* __restrict__ vvec, const void* __restrict__ ln_g,
    const void* __restrict__ ln_b, const void* __restrict__ comb_w,
    const void* __restrict__ comb_b, void* __restrict__ out)
{
    const int t = threadIdx.x;
    const int node0 = blockIdx.x * 4;
    const int lane = t & 63, w = t >> 6;

    if (t < 4) S.cnt[t] = g_nzc[node0 + t];
    for (int e = t; e < 512; e += 256) {
        const int n = e >> 7, k = e & 127;
        const int node = node0 + n;
        S.s_i[n][k] = g_s_buf[(size_t)node * 128 + k];
        ((float*)&S.comb4[k])[n] = g_hl[(size_t)node * 128 + k];
    }
    __syncthreads();
    #pragma unroll
    for (int n = 0; n < 4; ++n)
        for (int p = t; p < S.cnt[n]; p += 256)
            S.nzi[n][p] = g_nz[(size_t)(node0 + n) * NZMAX + p];
    __syncthreads();

    // scores: wave w owns node node0+w; lane covers dims lane, lane+64
    {
        const int bn = (node0 + w) / N_;
        const int cn = S.cnt[w];
        const float v0 = ldw<F32>(vvec, lane), v1 = ldw<F32>(vvec, 64 + lane);
        const float si0 = S.s_i[w][lane], si1 = S.s_i[w][lane + 64];
        for (int p = 0; p < cn; ++p) {
            const float* tj = g_t_buf + ((size_t)bn * N_ + S.nzi[w][p]) * 128;
            float a = v0 * tanh_f(si0 + tj[lane]) + v1 * tanh_f(si1 + tj[lane + 64]);
            #pragma unroll
            for (int off = 32; off > 0; off >>= 1) a += __shfl_xor(a, off);
            if (lane == 0) S.nzs[w][p] = a;
        }
    }
    __syncthreads();
    if (t < 4) {
        const int cn = S.cnt[t];
        float m = -1e30f;
        for (int p = 0; p < cn; ++p) m = fmaxf(m, S.nzs[t][p]);
        float ssum = 0.f;
        for (int p = 0; p < cn; ++p) { float e = __expf(S.nzs[t][p] - m); S.nzs[t][p] = e; ssum += e; }
        S.smv[t] = fast_rcp(ssum);
    }
    __syncthreads();

    // context
    const int o = t & 127;
    #pragma unroll
    for (int ps = 0; ps < 2; ++ps) {
        const int n = (t >> 7) + 2 * ps;
        const int bn = (node0 + n) / N_;
        const int cn = S.cnt[n];
        float acc = 0.f;
        for (int p = 0; p < cn; ++p)
            acc = fmaf(S.nzs[n][p], g_h_graph[((size_t)bn * N_ + S.nzi[n][p]) * 128 + o], acc);
        S.red[n][o] = acc * S.smv[n];
    }
    __syncthreads();

    // LayerNorm stats
    {
        float x0 = S.red[w][lane], x1 = S.red[w][lane + 64];
        float sm = x0 + x1, sq = x0 * x0 + x1 * x1;
        #pragma unroll
        for (int off = 32; off > 0; off >>= 1) {
            sm += __shfl_xor(sm, off);
            sq += __shfl_xor(sq, off);
        }
        if (lane == 0) {
            float mu = sm * (1.f / H_);
            float var = fmaxf(sq * (1.f / H_) - mu * mu, 0.f);
            S.mu_[w] = mu;
            S.rstd_[w] = __builtin_amdgcn_rsqf(var + 1e-5f);
        }
    }
    __syncthreads();
    for (int e = t; e < 512; e += 256) {
        const int n = e >> 7, k = e & 127;
        float xn = (S.red[n][k] - S.mu_[n]) * S.rstd_[n];
        ((float*)&S.comb4[128 + k])[n] = ldw<F32>(ln_g, k) * xn + ldw<F32>(ln_b, k);
    }
    __syncthreads();

    // combine: half = K-half; thread o reads raw comb_w row o contiguously
    {
        const int half = t >> 7;
        float a0 = 0.f, a1 = 0.f, a2 = 0.f, a3 = 0.f;
        #pragma unroll 4
        for (int k4 = 0; k4 < 32; ++k4) {          // row o, cols half*128 + [0,128)
            const float4 wv = ldw4<F32>(comb_w, (size_t)o * 64 + half * 32 + k4);
            const float* wp = (const float*)&wv;
            #pragma unroll
            for (int j = 0; j < 4; ++j) {
                const float4 cv = S.comb4[half * 128 + k4 * 4 + j];
                a0 = fmaf(cv.x, wp[j], a0); a1 = fmaf(cv.y, wp[j], a1);
                a2 = fmaf(cv.z, wp[j], a2); a3 = fmaf(cv.w, wp[j], a3);
            }
        }
        S.part[half][0][o] = a0; S.part[half][1][o] = a1;
        S.part[half][2][o] = a2; S.part[half][3][o] = a3;
    }
    __syncthreads();
    for (int e = t; e < 512; e += 256) {
        const int n = e >> 7, k = e & 127;
        stw<F32>(out, (size_t)(node0 + n) * 128 + k,
                 S.part[0][n][k] + S.part[1][n][k] + ldw<F32>(comb_b, k));
    }
}

__global__ __launch_bounds__(256) void kd3(
    const void* __restrict__ adj, const void* __restrict__ vvec,
    const void* __restrict__ ln_g, const void* __restrict__ ln_b,
    const void* __restrict__ comb_w, const void* __restrict__ comb_b,
    void* __restrict__ out)
{
    __shared__ LdsC S;
    if (probe_f32(adj)) d3_body<1>(S, vvec, ln_g, ln_b, comb_w, comb_b, out);
    else                d3_body<0>(S, vvec, ln_g, ln_b, comb_w, comb_b, out);
}

// ---------------------------------------------------------------------------
extern "C" void kernel_launch(void* const* d_in, const int* in_sizes, int n_in,
                              void* d_out, int out_size, void* d_ws, size_t ws_size,
                              hipStream_t stream)
{
    (void)in_sizes; (void)n_in; (void)out_size; (void)d_ws; (void)ws_size;
    const void* x      = d_in[0];
    const void* adj    = d_in[1];
    const void* h      = d_in[2];
    const void* c      = d_in[3];
    const void* W_ih   = d_in[4];
    const void* W_hh   = d_in[5];
    const void* b_ih   = d_in[6];
    const void* b_hh   = d_in[7];
    const void* gc_w   = d_in[8];
    const void* gc_b   = d_in[9];
    const void* Ws_w   = d_in[10];
    const void* Ws_b   = d_in[11];
    const void* Wt_w   = d_in[12];
    const void* Wt_b   = d_in[13];
    const void* vvec   = d_in[14];
    const void* ln_g   = d_in[15];
    const void* ln_b   = d_in[16];
    const void* comb_w = d_in[17];
    const void* comb_b = d_in[18];

    kd1<<<NBLK, 512, 0, stream>>>(x, adj, h, c, W_ih, W_hh, b_ih, b_hh, gc_w, d_out);
    kd2<<<NBLK, 256, 0, stream>>>(adj, gc_b, Ws_w, Ws_b, Wt_w, Wt_b);
    kd3<<<NBLK, 256, 0, stream>>>(adj, vvec, ln_g, ln_b, comb_w, comb_b, d_out);
}

// Round 4
// 141.145 us; speedup vs baseline: 2.0753x; 1.1535x over previous
//
#include <hip/hip_runtime.h>

#define B_ 4
#define N_ 325
#define I_ 64
#define H_ 128
#define NODES (B_ * N_)
#define NZMAX 64                    // max nz/row ~35 (5% of 325 + self-loop)
#define NBLK (NODES / 4)            // 325 blocks, 4 nodes each

typedef unsigned short u16;
typedef unsigned int u32;

// f32 weight scratch, written by k0_prep each launch (converts + transposes).
// Doubles as bf16->f32 conversion hoisting: hot GEMM loops read f32 only.
__device__ __align__(16) float g_WT   [192 * 512];   // [k][g]  gates weights
__device__ __align__(16) float g_gcw  [128 * 128];   // [k][o]
__device__ __align__(16) float g_WsT  [128 * 128];   // [k][o]
__device__ __align__(16) float g_WtT  [128 * 128];   // [k][o]
__device__ __align__(16) float g_combT[256 * 128];   // [k][o]
__device__ float g_bias[512];                        // b_ih + b_hh
__device__ float g_svec[896];  // [0]=gc_b [128]=Ws_b [256]=Wt_b [384]=v [512]=ln_g [640]=ln_b [768]=comb_b

// activation scratch
__device__ __align__(16) float g_support[(size_t)NODES * H_];
__device__ __align__(16) float g_h_graph[(size_t)NODES * H_];
__device__ __align__(16) float g_t_buf  [(size_t)NODES * H_];
__device__ __align__(16) float g_s_buf  [(size_t)NODES * H_];
__device__ __align__(16) float g_hl     [(size_t)NODES * H_];
__device__ u16   g_nz [(size_t)NODES * NZMAX];
__device__ float g_nzw[(size_t)NODES * NZMAX];
__device__ int   g_nzc[NODES];

__device__ __forceinline__ float bf2f(u16 u) { return __uint_as_float(((u32)u) << 16); }
__device__ __forceinline__ u16 f2bf(float f) {
    u32 u = __float_as_uint(f);
    u += 0x7fffu + ((u >> 16) & 1u);   // RNE
    return (u16)(u >> 16);
}
__device__ __forceinline__ float ldin(const void* p, size_t i, int f32) {
    return f32 ? ((const float*)p)[i] : bf2f(((const u16*)p)[i]);
}
__device__ __forceinline__ void stout(void* p, size_t i, float v, int f32) {
    if (f32) ((float*)p)[i] = v; else ((u16*)p)[i] = f2bf(v);
}
__device__ __forceinline__ float fast_rcp(float x) { return __builtin_amdgcn_rcpf(x); }
__device__ __forceinline__ float sigm(float x) { return fast_rcp(1.f + __expf(-x)); }
__device__ __forceinline__ float tanh_f(float x) {
    x = fminf(15.f, fmaxf(-15.f, x));
    float e = __expf(2.f * x);
    return (e - 1.f) * fast_rcp(e + 1.f);
}
// adj[0,0]==1.0 (self-loop): fp32 low16 = 0x0000, bf16 low16 = 0x3F80.
__device__ __forceinline__ int probe_f32(const void* adj) {
    return ((((const u32*)adj)[0] & 0xFFFFu) != 0x3F80u) ? 1 : 0;
}

// ---------------------------------------------------------------------------
// K0: convert + transpose all weights/biases to f32 scratch.
// ---------------------------------------------------------------------------
__global__ __launch_bounds__(256) void k0_prep(
    const void* __restrict__ W_ih, const void* __restrict__ W_hh,
    const void* __restrict__ b_ih, const void* __restrict__ b_hh,
    const void* __restrict__ gc_w, const void* __restrict__ gc_b,
    const void* __restrict__ Ws_w, const void* __restrict__ Ws_b,
    const void* __restrict__ Wt_w, const void* __restrict__ Wt_b,
    const void* __restrict__ vvec, const void* __restrict__ ln_g,
    const void* __restrict__ ln_b, const void* __restrict__ comb_w,
    const void* __restrict__ comb_b, const void* __restrict__ adj)
{
    const int f32 = probe_f32(adj);
    const int tid = blockIdx.x * 256 + threadIdx.x;
    const int nth = gridDim.x * 256;
    const int TOT = 98304 + 16384 * 3 + 32768 + 512 + 896;
    for (int e = tid; e < TOT; e += nth) {
        int i = e;
        if (i < 98304) {                                   // WT[k][g]
            const int k = i >> 9, g = i & 511;
            g_WT[i] = (k < 64) ? ldin(W_ih, (size_t)g * 64 + k, f32)
                               : ldin(W_hh, (size_t)g * 128 + (k - 64), f32);
            continue;
        }
        i -= 98304;
        if (i < 16384) { g_gcw[i] = ldin(gc_w, i, f32); continue; }
        i -= 16384;
        if (i < 16384) {                                   // WsT[k][o]
            const int k = i >> 7, o = i & 127;
            g_WsT[i] = ldin(Ws_w, (size_t)o * 128 + k, f32);
            continue;
        }
        i -= 16384;
        if (i < 16384) {
            const int k = i >> 7, o = i & 127;
            g_WtT[i] = ldin(Wt_w, (size_t)o * 128 + k, f32);
            continue;
        }
        i -= 16384;
        if (i < 32768) {                                   // combT[k][o]
            const int k = i >> 7, o = i & 127;
            g_combT[i] = ldin(comb_w, (size_t)o * 256 + k, f32);
            continue;
        }
        i -= 32768;
        if (i < 512) { g_bias[i] = ldin(b_ih, i, f32) + ldin(b_hh, i, f32); continue; }
        i -= 512;
        {
            const int seg = i >> 7, k = i & 127;
            const void* src = (seg == 0) ? gc_b : (seg == 1) ? Ws_b : (seg == 2) ? Wt_b :
                              (seg == 3) ? vvec : (seg == 4) ? ln_g : (seg == 5) ? ln_b : comb_b;
            g_svec[i] = ldin(src, k, f32);
        }
    }
}

// ---------------------------------------------------------------------------
// K1: 4 nodes/block, 512 threads. gates -> cell -> adjacency compaction ->
// support. Compaction lives here (k1 has thread slack) so k2 starts its
// gather immediately.
// ---------------------------------------------------------------------------
__global__ __launch_bounds__(512) void k1_lstm(
    const void* __restrict__ x, const void* __restrict__ h, const void* __restrict__ c,
    const void* __restrict__ adj, void* __restrict__ out)
{
    const int f32 = probe_f32(adj);
    __shared__ __align__(16) float4 xh4[192];    // [k] x {n0..n3}
    __shared__ __align__(16) float4 Gt4[512];    // [g] x {n0..n3}
    __shared__ __align__(16) float4 hl4[128];    // [k] x {n0..n3}
    __shared__ u16 nzi[4][NZMAX];
    __shared__ float nzv[4][NZMAX];
    __shared__ int cnt[4];
    const int node0 = blockIdx.x * 4;
    const int t = threadIdx.x;

    if (t < 4) cnt[t] = 0;
    // stage activations: xh4[k][n]
    for (int e = t; e < 768; e += 512) {
        const int n = e / 192, k = e % 192;
        const int node = node0 + n;
        ((float*)&xh4[k])[n] = (k < 64) ? ldin(x, (size_t)node * 64 + k, f32)
                                        : ldin(h, (size_t)node * 128 + (k - 64), f32);
    }
    __syncthreads();

    // gates: g = t; coalesced f32 scratch, broadcast activations
    {
        const int g = t;
        float a0 = 0.f, a1 = 0.f, a2 = 0.f, a3 = 0.f;
        #pragma unroll 8
        for (int k = 0; k < 192; ++k) {
            const float wv = g_WT[(size_t)k * 512 + g];
            const float4 xv = xh4[k];
            a0 = fmaf(xv.x, wv, a0); a1 = fmaf(xv.y, wv, a1);
            a2 = fmaf(xv.z, wv, a2); a3 = fmaf(xv.w, wv, a3);
        }
        const float bias = g_bias[g];
        Gt4[g] = make_float4(a0 + bias, a1 + bias, a2 + bias, a3 + bias);
    }
    __syncthreads();

    // cell nonlinearity: t = (n, hh)
    {
        const int n = t >> 7, hh = t & 127;
        const int node = node0 + n;
        float ig = ((const float*)&Gt4[hh])[n];
        float fg = ((const float*)&Gt4[128 + hh])[n];
        float gv = ((const float*)&Gt4[256 + hh])[n];
        float og = ((const float*)&Gt4[384 + hh])[n];
        float cl = sigm(fg) * ldin(c, (size_t)node * 128 + hh, f32) + sigm(ig) * tanh_f(gv);
        float hv = sigm(og) * tanh_f(cl);
        stout(out, (size_t)(NODES * H_) + (size_t)node * 128 + hh, cl, f32);
        g_hl[(size_t)node * 128 + hh] = hv;
        ((float*)&hl4[hh])[n] = hv;
    }
    // adjacency compaction (independent of cell; cnt zeroed before 1st sync)
    {
        const int n = t >> 7, jj = t & 127;
        const size_t row = (size_t)(node0 + n) * N_;
        for (int j = jj; j < N_; j += 128) {
            float a = ldin(adj, row + j, f32);
            if (a != 0.f) {
                int p = atomicAdd(&cnt[n], 1);
                if (p < NZMAX) { nzi[n][p] = (u16)j; nzv[n][p] = a; }
            }
        }
    }
    __syncthreads();

    // export nz lists
    if (t < 4) g_nzc[node0 + t] = min(cnt[t], NZMAX);
    #pragma unroll
    for (int n = 0; n < 4; ++n) {
        const int cnn = min(cnt[n], NZMAX);
        for (int p = t; p < cnn; p += 512) {
            g_nz [(size_t)(node0 + n) * NZMAX + p] = nzi[n][p];
            g_nzw[(size_t)(node0 + n) * NZMAX + p] = nzv[n][p];
        }
    }
    // support: coalesced gcw, broadcast hl
    {
        const int o = t & 127, n = t >> 7;     // n wave-uniform
        float acc = 0.f;
        #pragma unroll 8
        for (int k = 0; k < 128; ++k)
            acc = fmaf(((const float*)&hl4[k])[n], g_gcw[(size_t)k * 128 + o], acc);
        g_support[(size_t)(node0 + n) * 128 + o] = acc;
    }
}

// ---------------------------------------------------------------------------
// K2: 4 nodes/block, 512 threads. h_graph gather (1 pass) + s/t projections
// with K split in half across waves + LDS partial reduction.
// ---------------------------------------------------------------------------
__global__ __launch_bounds__(512) void k2_graph(const void* __restrict__ adj)
{
    (void)adj;
    __shared__ __align__(16) float4 hg4[128];    // [k] x {n0..n3}
    __shared__ u16 nzi[4][NZMAX];
    __shared__ float nzv[4][NZMAX];
    __shared__ int cnt[4];
    __shared__ float part[4][4][H_];             // [which*2+half][n][o]
    const int node0 = blockIdx.x * 4;
    const int t = threadIdx.x;

    if (t < 4) cnt[t] = g_nzc[node0 + t];
    __syncthreads();
    #pragma unroll
    for (int n = 0; n < 4; ++n) {
        const int cnn = cnt[n];
        for (int p = t; p < cnn; p += 512) {
            nzi[n][p] = g_nz [(size_t)(node0 + n) * NZMAX + p];
            nzv[n][p] = g_nzw[(size_t)(node0 + n) * NZMAX + p];
        }
    }
    __syncthreads();

    // h_graph gather: all 4 nodes in one pass (coalesced support rows)
    {
        const int n = t >> 7, o = t & 127;
        const int node = node0 + n;
        const int bn = node / N_;
        const int cnn = cnt[n];
        float acc = g_svec[o];                   // gc_b
        for (int p = 0; p < cnn; ++p)
            acc = fmaf(nzv[n][p], g_support[((size_t)bn * N_ + nzi[n][p]) * 128 + o], acc);
        g_h_graph[(size_t)node * 128 + o] = acc;
        ((float*)&hg4[o])[n] = acc;
    }
    __syncthreads();

    // s/t projections: which = s/t, half = K-half; partials via LDS
    {
        const int o = t & 127;
        const int which = (t >> 7) & 1;
        const int half  = t >> 8;
        const float* WT = which ? g_WtT : g_WsT;
        const int k0 = half * 64;
        float a0 = 0.f, a1 = 0.f, a2 = 0.f, a3 = 0.f;
        #pragma unroll 8
        for (int kk = 0; kk < 64; ++kk) {
            const int k = k0 + kk;
            const float wv = WT[(size_t)k * 128 + o];
            const float4 hv = hg4[k];
            a0 = fmaf(hv.x, wv, a0); a1 = fmaf(hv.y, wv, a1);
            a2 = fmaf(hv.z, wv, a2); a3 = fmaf(hv.w, wv, a3);
        }
        const int s = which * 2 + half;
        part[s][0][o] = a0; part[s][1][o] = a1;
        part[s][2][o] = a2; part[s][3][o] = a3;
    }
    __syncthreads();
    for (int e = t; e < 1024; e += 512) {
        const int which = e >> 9, n = (e >> 7) & 3, o = e & 127;
        const float vsum = part[which * 2][n][o] + part[which * 2 + 1][n][o]
                         + g_svec[128 + which * 128 + o];
        float* dst = which ? g_t_buf : g_s_buf;
        dst[(size_t)(node0 + n) * 128 + o] = vsum;
    }
}

// ---------------------------------------------------------------------------
// K3: 4 nodes/block, 512 threads. scores (2 waves/node) + softmax + context
// (1 pass) + LN + combine (K-quarters).
// ---------------------------------------------------------------------------
__global__ __launch_bounds__(512) void k3_attn(
    const void* __restrict__ adj, void* __restrict__ out)
{
    const int f32 = probe_f32(adj);
    __shared__ __align__(16) float4 hl4[128];    // h_lstm  [k] x {n0..n3}
    __shared__ __align__(16) float4 att4[128];   // normalized attention
    __shared__ float s_i[4][H_];
    __shared__ float red[4][H_];
    __shared__ float nzs[4][NZMAX];
    __shared__ u16 nzi[4][NZMAX];
    __shared__ float part[4][4][H_];
    __shared__ float mu_[4], rstd_[4], smv[4];
    __shared__ int cnt[4];
    const int node0 = blockIdx.x * 4;
    const int t = threadIdx.x;
    const int lane = t & 63, w = t >> 6;

    if (t < 4) cnt[t] = g_nzc[node0 + t];
    for (int e = t; e < 512; e += 512) {
        const int n = e >> 7, k = e & 127;
        const int node = node0 + n;
        s_i[n][k] = g_s_buf[(size_t)node * 128 + k];
        ((float*)&hl4[k])[n] = g_hl[(size_t)node * 128 + k];
    }
    __syncthreads();
    #pragma unroll
    for (int n = 0; n < 4; ++n)
        for (int p = t; p < cnt[n]; p += 512)
            nzi[n][p] = g_nz[(size_t)(node0 + n) * NZMAX + p];
    __syncthreads();

    // scores: 2 waves per node; lane covers dims lane, lane+64
    {
        const int n = w & 3;
        const int bn = (node0 + n) / N_;
        const int cn = cnt[n];
        const float v0 = g_svec[384 + lane], v1 = g_svec[384 + 64 + lane];
        const float si0 = s_i[n][lane], si1 = s_i[n][lane + 64];
        for (int p = (w >> 2); p < cn; p += 2) {
            const float* tj = g_t_buf + ((size_t)bn * N_ + nzi[n][p]) * 128;
            float a = v0 * tanh_f(si0 + tj[lane]) + v1 * tanh_f(si1 + tj[lane + 64]);
            #pragma unroll
            for (int off = 32; off > 0; off >>= 1) a += __shfl_xor(a, off);
            if (lane == 0) nzs[n][p] = a;
        }
    }
    __syncthreads();
    if (t < 4) {
        const int cn = cnt[t];
        float m = -1e30f;
        for (int p = 0; p < cn; ++p) m = fmaxf(m, nzs[t][p]);
        float ssum = 0.f;
        for (int p = 0; p < cn; ++p) { float e = __expf(nzs[t][p] - m); nzs[t][p] = e; ssum += e; }
        smv[t] = fast_rcp(ssum);
    }
    __syncthreads();

    // context: all 4 nodes in one pass (coalesced h_graph rows)
    {
        const int n = t >> 7, o = t & 127;
        const int bn = (node0 + n) / N_;
        const int cn = cnt[n];
        float acc = 0.f;
        for (int p = 0; p < cn; ++p)
            acc = fmaf(nzs[n][p], g_h_graph[((size_t)bn * N_ + nzi[n][p]) * 128 + o], acc);
        red[n][o] = acc * smv[n];
    }
    __syncthreads();

    // LayerNorm stats: wave w -> node w (waves 0..3)
    if (w < 4) {
        float x0 = red[w][lane], x1 = red[w][lane + 64];
        float sm = x0 + x1, sq = x0 * x0 + x1 * x1;
        #pragma unroll
        for (int off = 32; off > 0; off >>= 1) {
            sm += __shfl_xor(sm, off);
            sq += __shfl_xor(sq, off);
        }
        if (lane == 0) {
            float mu = sm * (1.f / H_);
            float var = fmaxf(sq * (1.f / H_) - mu * mu, 0.f);
            mu_[w] = mu;
            rstd_[w] = __builtin_amdgcn_rsqf(var + 1e-5f);
        }
    }
    __syncthreads();
    {
        const int n = t >> 7, k = t & 127;
        float xn = (red[n][k] - mu_[n]) * rstd_[n];
        ((float*)&att4[k])[n] = g_svec[512 + k] * xn + g_svec[640 + k];
    }
    __syncthreads();

    // combine: quarter q covers K-slice [q*64, q*64+64); k<128 -> hl4
    {
        const int o = t & 127, q = t >> 7;     // q wave-uniform
        const float4* src = (q < 2) ? hl4 : att4;
        const int kb = (q < 2) ? q * 64 : (q - 2) * 64;
        const int k0 = q * 64;
        float a0 = 0.f, a1 = 0.f, a2 = 0.f, a3 = 0.f;
        #pragma unroll 8
        for (int kk = 0; kk < 64; ++kk) {
            const float wv = g_combT[(size_t)(k0 + kk) * 128 + o];
            const float4 cv = src[kb + kk];
            a0 = fmaf(cv.x, wv, a0); a1 = fmaf(cv.y, wv, a1);
            a2 = fmaf(cv.z, wv, a2); a3 = fmaf(cv.w, wv, a3);
        }
        part[q][0][o] = a0; part[q][1][o] = a1;
        part[q][2][o] = a2; part[q][3][o] = a3;
    }
    __syncthreads();
    {
        const int n = t >> 7, k = t & 127;
        stout(out, (size_t)(node0 + n) * 128 + k,
              part[0][n][k] + part[1][n][k] + part[2][n][k] + part[3][n][k]
              + g_svec[768 + k], f32);
    }
}

// ---------------------------------------------------------------------------
extern "C" void kernel_launch(void* const* d_in, const int* in_sizes, int n_in,
                              void* d_out, int out_size, void* d_ws, size_t ws_size,
                              hipStream_t stream)
{
    (void)in_sizes; (void)n_in; (void)out_size; (void)d_ws; (void)ws_size;
    const void* x      = d_in[0];
    const void* adj    = d_in[1];
    const void* h      = d_in[2];
    const void* c      = d_in[3];
    const void* W_ih   = d_in[4];
    const void* W_hh   = d_in[5];
    const void* b_ih   = d_in[6];
    const void* b_hh   = d_in[7];
    const void* gc_w   = d_in[8];
    const void* gc_b   = d_in[9];
    const void* Ws_w   = d_in[10];
    const void* Ws_b   = d_in[11];
    const void* Wt_w   = d_in[12];
    const void* Wt_b   = d_in[13];
    const void* vvec   = d_in[14];
    const void* ln_g   = d_in[15];
    const void* ln_b   = d_in[16];
    const void* comb_w = d_in[17];
    const void* comb_b = d_in[18];

    k0_prep <<<256, 256, 0, stream>>>(W_ih, W_hh, b_ih, b_hh, gc_w, gc_b,
                                      Ws_w, Ws_b, Wt_w, Wt_b, vvec, ln_g, ln_b,
                                      comb_w, comb_b, adj);
    k1_lstm <<<NBLK, 512, 0, stream>>>(x, h, c, adj, d_out);
    k2_graph<<<NBLK, 512, 0, stream>>>(adj);
    k3_attn <<<NBLK, 512, 0, stream>>>(adj, d_out);
}